// Round 1
// baseline (824.136 us; speedup 1.0000x reference)
//
#include <hip/hip_runtime.h>
#include <hip/hip_bf16.h>
#include <type_traits>

typedef __hip_bfloat16 bf16;
typedef __attribute__((ext_vector_type(8))) short bf16x8;
typedef __attribute__((ext_vector_type(4))) float f32x4;

#define N_LOC 4096
#define DMODEL 512
#define NHEAD 4
#define DK 128
#define DV 256

__device__ __forceinline__ bf16 to_bf16(float f) { return __float2bfloat16(f); }

// ---------------- conversion / packing ----------------
__global__ __launch_bounds__(256) void convert_bf16(const float* __restrict__ in,
                                                    bf16* __restrict__ out, int n) {
  for (int i = blockIdx.x * 256 + threadIdx.x; i < n; i += gridDim.x * 256)
    out[i] = to_bf16(in[i]);
}

// out[(h*DH + t)*512 + d] = in[(h*512 + d)*DH + t]   (W: [H][512][DH] -> Bt: [H*DH][512])
__global__ __launch_bounds__(256) void pack_w(const float* __restrict__ in,
                                              bf16* __restrict__ out, int DH, int n) {
  for (int o = blockIdx.x * 256 + threadIdx.x; o < n; o += gridDim.x * 256) {
    int row = o >> 9;        // /512
    int d = o & 511;
    int h = row / DH;
    int t = row - h * DH;
    out[o] = to_bf16(in[(h * 512 + d) * DH + t]);
  }
}

// ---------------- generic GEMM: C[M][N] = A[M][K] * Bt[N][K]^T ----------------
template <typename OutT>
__global__ __launch_bounds__(256) void gemm_bt(const bf16* __restrict__ A,
                                               const bf16* __restrict__ Bt,
                                               OutT* __restrict__ C, int M, int N, int K) {
  const int LD = 72;  // 64 + 8 pad: 144B row stride, 16B-aligned, conflict-free b128
  __shared__ bf16 As[64 * LD];
  __shared__ bf16 Bs[64 * LD];
  int tid = threadIdx.x;
  int lane = tid & 63, w = tid >> 6;
  int quad = lane >> 4, l16 = lane & 15;
  int wm = (w >> 1) * 32, wn = (w & 1) * 32;
  int m0 = blockIdx.x * 64, n0 = blockIdx.y * 64;

  f32x4 acc[2][2] = {};
  for (int k0 = 0; k0 < K; k0 += 64) {
    for (int i = tid; i < 64 * 8; i += 256) {
      int r = i >> 3, c = (i & 7) * 8;
      *(bf16x8*)&As[r * LD + c] = *(const bf16x8*)&A[(long)(m0 + r) * K + k0 + c];
      *(bf16x8*)&Bs[r * LD + c] = *(const bf16x8*)&Bt[(long)(n0 + r) * K + k0 + c];
    }
    __syncthreads();
#pragma unroll
    for (int kk = 0; kk < 2; kk++) {
      bf16x8 af[2], bfr[2];
#pragma unroll
      for (int i = 0; i < 2; i++)
        af[i] = *(const bf16x8*)&As[(wm + i * 16 + l16) * LD + kk * 32 + quad * 8];
#pragma unroll
      for (int j = 0; j < 2; j++)
        bfr[j] = *(const bf16x8*)&Bs[(wn + j * 16 + l16) * LD + kk * 32 + quad * 8];
#pragma unroll
      for (int i = 0; i < 2; i++)
#pragma unroll
        for (int j = 0; j < 2; j++)
          acc[i][j] = __builtin_amdgcn_mfma_f32_16x16x32_bf16(af[i], bfr[j], acc[i][j], 0, 0, 0);
    }
    __syncthreads();
  }
  // C/D layout: col = lane&15, row = quad*4 + r
#pragma unroll
  for (int i = 0; i < 2; i++)
#pragma unroll
    for (int j = 0; j < 2; j++)
#pragma unroll
      for (int r = 0; r < 4; r++) {
        long row = m0 + wm + i * 16 + quad * 4 + r;
        long col = n0 + wn + j * 16 + l16;
        if constexpr (std::is_same<OutT, bf16>::value)
          C[row * N + col] = to_bf16(acc[i][j][r]);
        else
          C[row * N + col] = acc[i][j][r];
      }
}

// ---------------- transpose (R x C) -> (C x R), bf16 ----------------
__global__ __launch_bounds__(256) void transpose_bf16(const bf16* __restrict__ in,
                                                      bf16* __restrict__ out, int R, int Cc) {
  __shared__ bf16 t[64][65];
  int r0 = blockIdx.x * 64, c0 = blockIdx.y * 64;
  for (int i = threadIdx.x; i < 64 * 64; i += 256) {
    int r = i >> 6, c = i & 63;
    t[r][c] = in[(long)(r0 + r) * Cc + c0 + c];
  }
  __syncthreads();
  for (int i = threadIdx.x; i < 64 * 64; i += 256) {
    int c = i >> 6, r = i & 63;
    out[(long)(c0 + c) * R + r0 + r] = t[r][c];
  }
}

// ---------------- fused attention ----------------
// qb,kb: [N][H*DK]; vT: [H*DV][N]; x: [N][H*DV]
// block = 512 threads (8 waves), 64 queries per block, loop over 64-key tiles.
// Unnormalized softmax (|s|<=~0.4, no overflow); L via ones-column of v.
__global__ __launch_bounds__(512) void attn(const bf16* __restrict__ qb,
                                            const bf16* __restrict__ kb,
                                            const bf16* __restrict__ vT,
                                            bf16* __restrict__ x) {
  const int KLD = 136;  // 128+8
  const int VLD = 72;   // 64+8
  const int PLD = 64;   // unpadded (LDS budget) — minor bank conflicts accepted
  __shared__ bf16 kt[64 * KLD];    // [key][dk]
  __shared__ bf16 vt[272 * VLD];   // [dv'][key]; rows 256..271: ones-column trick
  __shared__ bf16 pt[64 * PLD];    // [q][key]
  __shared__ float Lrow[64];

  const int head = blockIdx.x & 3;          // head = blk%4, XCD = blk%8 -> 1 head per XCD
  const int q0 = (blockIdx.x >> 2) * 64;
  int tid = threadIdx.x;
  int lane = tid & 63, w = tid >> 6;        // 8 waves
  int quad = lane >> 4, l16 = lane & 15;
  int qr = w >> 1;                          // q tile-row 0..3 (rows qr*16..)
  int odd = w & 1;
  int sc0 = odd * 2;                        // S key tile-cols {0,1} or {2,3}
  int NC = odd ? 8 : 9;                     // PV dv tile-cols: even 0..8, odd 9..16
  int cbase = odd ? 9 : 0;

  // init ones/zeros rows of vt (written once, staging only touches rows 0..255)
  for (int i = tid; i < 16 * 64; i += 512) {
    int r = 256 + (i >> 6), c = i & 63;
    vt[r * VLD + c] = (r == 256) ? to_bf16(1.0f) : to_bf16(0.0f);
  }
  // q fragments direct from global (A-layout: m=l16, k=quad*8+j)
  bf16x8 qf[4];
  {
    const bf16* qrow = &qb[(long)(q0 + qr * 16 + l16) * (NHEAD * DK) + head * DK];
#pragma unroll
    for (int kk = 0; kk < 4; kk++) qf[kk] = *(const bf16x8*)&qrow[kk * 32 + quad * 8];
  }
  f32x4 oacc[9] = {};
  const float scale = 1.0f / 64.0f;  // 1/sqrt(4096)
  __syncthreads();

  for (int key0 = 0; key0 < N_LOC; key0 += 64) {
    // stage k tile: 64 keys x 128 dk
    for (int i = tid; i < 64 * 16; i += 512) {
      int r = i >> 4, c = (i & 15) * 8;
      *(bf16x8*)&kt[r * KLD + c] =
          *(const bf16x8*)&kb[(long)(key0 + r) * (NHEAD * DK) + head * DK + c];
    }
    // stage vT tile: 256 dv x 64 keys
    for (int i = tid; i < 256 * 8; i += 512) {
      int r = i >> 3, c = (i & 7) * 8;
      *(bf16x8*)&vt[r * VLD + c] =
          *(const bf16x8*)&vT[(long)(head * DV + r) * N_LOC + key0 + c];
    }
    __syncthreads();

    // S = q @ k^T for this wave's 16x32 slice
    f32x4 sacc[2] = {};
#pragma unroll
    for (int kk = 0; kk < 4; kk++) {
#pragma unroll
      for (int t = 0; t < 2; t++) {
        bf16x8 bfr = *(const bf16x8*)&kt[((sc0 + t) * 16 + l16) * KLD + kk * 32 + quad * 8];
        sacc[t] = __builtin_amdgcn_mfma_f32_16x16x32_bf16(qf[kk], bfr, sacc[t], 0, 0, 0);
      }
    }
    // exp (unnormalized softmax) -> P in LDS, A-layout friendly [q][key]
#pragma unroll
    for (int t = 0; t < 2; t++)
#pragma unroll
      for (int r = 0; r < 4; r++) {
        float p = __expf(sacc[t][r] * scale);
        pt[(qr * 16 + quad * 4 + r) * PLD + (sc0 + t) * 16 + l16] = to_bf16(p);
      }
    __syncthreads();

    // O += P @ v  (contraction over 64 keys; B-operand from vt = v^T, contiguous reads)
#pragma unroll
    for (int kk = 0; kk < 2; kk++) {
      bf16x8 pf = *(const bf16x8*)&pt[(qr * 16 + l16) * PLD + kk * 32 + quad * 8];
#pragma unroll
      for (int c = 0; c < 9; c++) {
        if (c >= NC) break;
        bf16x8 vf = *(const bf16x8*)&vt[((cbase + c) * 16 + l16) * VLD + kk * 32 + quad * 8];
        oacc[c] = __builtin_amdgcn_mfma_f32_16x16x32_bf16(pf, vf, oacc[c], 0, 0, 0);
      }
    }
    __syncthreads();
  }

  // L lives in odd waves' oacc[7] (tile-col 16), col 0 (l16==0)
  if (odd && l16 == 0) {
#pragma unroll
    for (int r = 0; r < 4; r++) Lrow[qr * 16 + quad * 4 + r] = oacc[7][r];
  }
  __syncthreads();

  // normalize + write x[n][h*DV + dv]
  for (int c = 0; c < NC; c++) {
    int col = cbase + c;
    if (col == 16) continue;
#pragma unroll
    for (int r = 0; r < 4; r++) {
      int row = qr * 16 + quad * 4 + r;
      float v = oacc[c][r] / Lrow[row];
      x[(long)(q0 + row) * (NHEAD * DV) + head * DV + col * 16 + l16] = to_bf16(v);
    }
  }
}

// ---------------- launch ----------------
extern "C" void kernel_launch(void* const* d_in, const int* in_sizes, int n_in,
                              void* d_out, int out_size, void* d_ws, size_t ws_size,
                              hipStream_t stream) {
  const float* Q  = (const float*)d_in[0];
  const float* Km = (const float*)d_in[1];
  const float* V  = (const float*)d_in[2];
  const float* Wq = (const float*)d_in[3];
  const float* Wk = (const float*)d_in[4];
  const float* Wv = (const float*)d_in[5];
  const float* Wo = (const float*)d_in[6];
  float* out = (float*)d_out;

  bf16* ws  = (bf16*)d_ws;
  bf16* Qb  = ws;                 // 4096x512
  bf16* Kb  = Qb + 2097152;
  bf16* Vb  = Kb + 2097152;
  bf16* Wqt = Vb + 2097152;       // 512x512  (Bt)
  bf16* Wkt = Wqt + 262144;
  bf16* Wvt = Wkt + 262144;       // 1024x512 (Bt)
  bf16* Wob = Wvt + 524288;       // 512x1024 (Bt = Wo as-is)
  bf16* qb  = Wob + 524288;       // 4096x512
  bf16* kb  = qb + 2097152;
  bf16* vb  = kb + 2097152;       // 4096x1024
  bf16* vT  = vb + 4194304;       // 1024x4096
  bf16* x   = vT + 4194304;       // 4096x1024

  convert_bf16<<<1024, 256, 0, stream>>>(Q, Qb, 2097152);
  convert_bf16<<<1024, 256, 0, stream>>>(Km, Kb, 2097152);
  convert_bf16<<<1024, 256, 0, stream>>>(V, Vb, 2097152);
  convert_bf16<<<512, 256, 0, stream>>>(Wo, Wob, 524288);
  pack_w<<<512, 256, 0, stream>>>(Wq, Wqt, 128, 262144);
  pack_w<<<512, 256, 0, stream>>>(Wk, Wkt, 128, 262144);
  pack_w<<<512, 256, 0, stream>>>(Wv, Wvt, 256, 524288);

  gemm_bt<bf16><<<dim3(64, 8), 256, 0, stream>>>(Qb, Wqt, qb, 4096, 512, 512);
  gemm_bt<bf16><<<dim3(64, 8), 256, 0, stream>>>(Kb, Wkt, kb, 4096, 512, 512);
  gemm_bt<bf16><<<dim3(64, 16), 256, 0, stream>>>(Vb, Wvt, vb, 4096, 1024, 512);
  transpose_bf16<<<dim3(64, 16), 256, 0, stream>>>(vb, vT, 4096, 1024);

  attn<<<256, 512, 0, stream>>>(qb, kb, vT, x);

  gemm_bt<float><<<dim3(64, 8), 256, 0, stream>>>(x, Wob, out, 4096, 512, 1024);
}

// Round 2
// 360.549 us; speedup vs baseline: 2.2858x; 2.2858x over previous
//
#include <hip/hip_runtime.h>
#include <hip/hip_bf16.h>
#include <type_traits>

typedef __hip_bfloat16 bf16;
typedef __attribute__((ext_vector_type(8))) short bf16x8;
typedef __attribute__((ext_vector_type(4))) float f32x4;

#define N_LOC 4096
#define DMODEL 512
#define NHEAD 4
#define DK 128
#define DV 256

__device__ __forceinline__ bf16 to_bf16(float f) { return __float2bfloat16(f); }

// ---------------- conversion / packing ----------------
__global__ __launch_bounds__(256) void convert_bf16(const float* __restrict__ in,
                                                    bf16* __restrict__ out, int n) {
  // 8 floats per thread, vectorized
  for (int i = (blockIdx.x * 256 + threadIdx.x) * 8; i < n; i += gridDim.x * 256 * 8) {
    float4 a = *(const float4*)&in[i];
    float4 b = *(const float4*)&in[i + 4];
    union { bf16 h[8]; bf16x8 v; } u;
    u.h[0] = to_bf16(a.x); u.h[1] = to_bf16(a.y); u.h[2] = to_bf16(a.z); u.h[3] = to_bf16(a.w);
    u.h[4] = to_bf16(b.x); u.h[5] = to_bf16(b.y); u.h[6] = to_bf16(b.z); u.h[7] = to_bf16(b.w);
    *(bf16x8*)&out[i] = u.v;
  }
}

// out[(h*DH + t)*512 + d] = in[(h*512 + d)*DH + t]   (W: [H][512][DH] -> Bt: [H*DH][512])
__global__ __launch_bounds__(256) void pack_w(const float* __restrict__ in,
                                              bf16* __restrict__ out, int DH, int n) {
  for (int o = blockIdx.x * 256 + threadIdx.x; o < n; o += gridDim.x * 256) {
    int row = o >> 9;        // /512
    int d = o & 511;
    int h = row / DH;
    int t = row - h * DH;
    out[o] = to_bf16(in[(h * 512 + d) * DH + t]);
  }
}

// ---------------- generic GEMM: C[M][N] = A[M][K] * Bt[N][K]^T ----------------
template <typename OutT>
__global__ __launch_bounds__(256) void gemm_bt(const bf16* __restrict__ A,
                                               const bf16* __restrict__ Bt,
                                               OutT* __restrict__ C, int M, int N, int K) {
  const int LD = 72;  // 64 + 8 pad: 144B row stride, 16B-aligned, conflict-free b128
  __shared__ bf16 As[64 * LD];
  __shared__ bf16 Bs[64 * LD];
  int tid = threadIdx.x;
  int lane = tid & 63, w = tid >> 6;
  int quad = lane >> 4, l16 = lane & 15;
  int wm = (w >> 1) * 32, wn = (w & 1) * 32;
  int m0 = blockIdx.x * 64, n0 = blockIdx.y * 64;

  f32x4 acc[2][2] = {};
  for (int k0 = 0; k0 < K; k0 += 64) {
    for (int i = tid; i < 64 * 8; i += 256) {
      int r = i >> 3, c = (i & 7) * 8;
      *(bf16x8*)&As[r * LD + c] = *(const bf16x8*)&A[(long)(m0 + r) * K + k0 + c];
      *(bf16x8*)&Bs[r * LD + c] = *(const bf16x8*)&Bt[(long)(n0 + r) * K + k0 + c];
    }
    __syncthreads();
#pragma unroll
    for (int kk = 0; kk < 2; kk++) {
      bf16x8 af[2], bfr[2];
#pragma unroll
      for (int i = 0; i < 2; i++)
        af[i] = *(const bf16x8*)&As[(wm + i * 16 + l16) * LD + kk * 32 + quad * 8];
#pragma unroll
      for (int j = 0; j < 2; j++)
        bfr[j] = *(const bf16x8*)&Bs[(wn + j * 16 + l16) * LD + kk * 32 + quad * 8];
#pragma unroll
      for (int i = 0; i < 2; i++)
#pragma unroll
        for (int j = 0; j < 2; j++)
          acc[i][j] = __builtin_amdgcn_mfma_f32_16x16x32_bf16(af[i], bfr[j], acc[i][j], 0, 0, 0);
    }
    __syncthreads();
  }
  // C/D layout: col = lane&15, row = quad*4 + r
#pragma unroll
  for (int i = 0; i < 2; i++)
#pragma unroll
    for (int j = 0; j < 2; j++)
#pragma unroll
      for (int r = 0; r < 4; r++) {
        long row = m0 + wm + i * 16 + quad * 4 + r;
        long col = n0 + wn + j * 16 + l16;
        if constexpr (std::is_same<OutT, bf16>::value)
          C[row * N + col] = to_bf16(acc[i][j][r]);
        else
          C[row * N + col] = acc[i][j][r];
      }
}

// ---------------- transpose (R x C) -> (C x R), bf16 ----------------
__global__ __launch_bounds__(256) void transpose_bf16(const bf16* __restrict__ in,
                                                      bf16* __restrict__ out, int R, int Cc) {
  __shared__ bf16 t[64][65];
  int r0 = blockIdx.x * 64, c0 = blockIdx.y * 64;
  for (int i = threadIdx.x; i < 64 * 64; i += 256) {
    int r = i >> 6, c = i & 63;
    t[r][c] = in[(long)(r0 + r) * Cc + c0 + c];
  }
  __syncthreads();
  for (int i = threadIdx.x; i < 64 * 64; i += 256) {
    int c = i >> 6, r = i & 63;
    out[(long)(c0 + c) * R + r0 + r] = t[r][c];
  }
}

// ---------------- fused attention ----------------
// qb,kb: [N][H*DK]; vT: [H*DV][N]; x: [N][H*DV]
// block = 512 threads (8 waves), 64 queries per block, loop over 64-key tiles.
// Unnormalized softmax (|s|<=~0.4, no overflow); L via ones-column of v.
//
// Wave layout: qr = w>>1 selects q tile-row (16 rows). odd = w&1 selects
// column set: even waves own dv tile-cols 0..8 (acc[0..8]); odd waves own
// tile-cols 9..16 (acc[0..7]; col 16 is the ones-column -> row-sum L).
// ALL acc indexing is compile-time (full unroll, wave-uniform guards) so the
// accumulators stay in VGPRs — round 1's runtime-bounded loops spilled the
// whole array to scratch (VGPR=52, 1.2 GB scratch writes, 685 us).
__global__ __launch_bounds__(512) void attn(const bf16* __restrict__ qb,
                                            const bf16* __restrict__ kb,
                                            const bf16* __restrict__ vT,
                                            bf16* __restrict__ x) {
  const int KLD = 136;  // 128+8
  const int VLD = 72;   // 64+8
  const int PLD = 64;   // unpadded (LDS budget)
  __shared__ bf16 kt[64 * KLD];    // [key][dk]
  __shared__ bf16 vt[272 * VLD];   // [dv'][key]; rows 256..271: ones-column trick
  __shared__ bf16 pt[64 * PLD];    // [q][key]
  __shared__ float Lrow[64];

  const int head = blockIdx.x & 3;          // head = blk%4, XCD = blk%8 -> 1 head per XCD
  const int q0 = (blockIdx.x >> 2) * 64;
  int tid = threadIdx.x;
  int lane = tid & 63, w = tid >> 6;        // 8 waves
  int quad = lane >> 4, l16 = lane & 15;
  int qr = w >> 1;                          // q tile-row 0..3
  int odd = w & 1;
  int sc0 = odd * 2;                        // S key tile-cols {0,1} or {2,3}
  int cbase = odd ? 9 : 0;

  // init ones/zeros rows of vt (staging only touches rows 0..255)
  for (int i = tid; i < 16 * 64; i += 512) {
    int r = 256 + (i >> 6), c = i & 63;
    vt[r * VLD + c] = (r == 256) ? to_bf16(1.0f) : to_bf16(0.0f);
  }
  // q fragments direct from global (A-layout: m=l16, k=quad*8+j)
  bf16x8 qf[4];
  {
    const bf16* qrow = &qb[(long)(q0 + qr * 16 + l16) * (NHEAD * DK) + head * DK];
#pragma unroll
    for (int kk = 0; kk < 4; kk++) qf[kk] = *(const bf16x8*)&qrow[kk * 32 + quad * 8];
  }
  f32x4 oacc[9] = {};
  const float scale = 1.0f / 64.0f;  // 1/sqrt(4096)
  __syncthreads();

  for (int key0 = 0; key0 < N_LOC; key0 += 64) {
    // stage k tile: 64 keys x 128 dk
    for (int i = tid; i < 64 * 16; i += 512) {
      int r = i >> 4, c = (i & 15) * 8;
      *(bf16x8*)&kt[r * KLD + c] =
          *(const bf16x8*)&kb[(long)(key0 + r) * (NHEAD * DK) + head * DK + c];
    }
    // stage vT tile: 256 dv x 64 keys
    for (int i = tid; i < 256 * 8; i += 512) {
      int r = i >> 3, c = (i & 7) * 8;
      *(bf16x8*)&vt[r * VLD + c] =
          *(const bf16x8*)&vT[(long)(head * DV + r) * N_LOC + key0 + c];
    }
    __syncthreads();

    // S = q @ k^T for this wave's 16x32 slice
    f32x4 sacc[2] = {};
#pragma unroll
    for (int kk = 0; kk < 4; kk++) {
#pragma unroll
      for (int t = 0; t < 2; t++) {
        bf16x8 bfr = *(const bf16x8*)&kt[((sc0 + t) * 16 + l16) * KLD + kk * 32 + quad * 8];
        sacc[t] = __builtin_amdgcn_mfma_f32_16x16x32_bf16(qf[kk], bfr, sacc[t], 0, 0, 0);
      }
    }
    // exp (unnormalized softmax) -> P in LDS, [q][key]
#pragma unroll
    for (int t = 0; t < 2; t++)
#pragma unroll
      for (int r = 0; r < 4; r++) {
        float p = __expf(sacc[t][r] * scale);
        pt[(qr * 16 + quad * 4 + r) * PLD + (sc0 + t) * 16 + l16] = to_bf16(p);
      }
    __syncthreads();

    // O += P @ v  (contraction over 64 keys; B-operand from vt = v^T)
    // Static unroll, compile-time acc indices, wave-uniform guard.
#pragma unroll
    for (int kk = 0; kk < 2; kk++) {
      bf16x8 pf = *(const bf16x8*)&pt[(qr * 16 + l16) * PLD + kk * 32 + quad * 8];
#pragma unroll
      for (int c = 0; c < 9; c++) {
        if (odd && c == 8) continue;  // odd waves use acc[0..7] only
        bf16x8 vf = *(const bf16x8*)&vt[((cbase + c) * 16 + l16) * VLD + kk * 32 + quad * 8];
        oacc[c] = __builtin_amdgcn_mfma_f32_16x16x32_bf16(pf, vf, oacc[c], 0, 0, 0);
      }
    }
    __syncthreads();
  }

  // L lives in odd waves' acc[7] (tile-col 16), col-in-tile 0 (l16==0)
  if (odd && l16 == 0) {
#pragma unroll
    for (int r = 0; r < 4; r++) Lrow[qr * 16 + quad * 4 + r] = oacc[7][r];
  }
  __syncthreads();

  // normalize + write x[n][h*DV + dv] — fully static unroll
#pragma unroll
  for (int c = 0; c < 9; c++) {
    if (odd && c >= 7) continue;  // c==7 is the ones/L column, c==8 unused
    int col = cbase + c;
#pragma unroll
    for (int r = 0; r < 4; r++) {
      int row = qr * 16 + quad * 4 + r;
      float v = oacc[c][r] / Lrow[row];
      x[(long)(q0 + row) * (NHEAD * DV) + head * DV + col * 16 + l16] = to_bf16(v);
    }
  }
}

// ---------------- launch ----------------
extern "C" void kernel_launch(void* const* d_in, const int* in_sizes, int n_in,
                              void* d_out, int out_size, void* d_ws, size_t ws_size,
                              hipStream_t stream) {
  const float* Q  = (const float*)d_in[0];
  const float* Km = (const float*)d_in[1];
  const float* V  = (const float*)d_in[2];
  const float* Wq = (const float*)d_in[3];
  const float* Wk = (const float*)d_in[4];
  const float* Wv = (const float*)d_in[5];
  const float* Wo = (const float*)d_in[6];
  float* out = (float*)d_out;

  bf16* ws  = (bf16*)d_ws;
  bf16* Qb  = ws;                 // 4096x512
  bf16* Kb  = Qb + 2097152;
  bf16* Vb  = Kb + 2097152;
  bf16* Wqt = Vb + 2097152;       // 512x512  (Bt)
  bf16* Wkt = Wqt + 262144;
  bf16* Wvt = Wkt + 262144;       // 1024x512 (Bt)
  bf16* Wob = Wvt + 524288;       // 512x1024 (Bt = Wo as-is)
  bf16* qb  = Wob + 524288;       // 4096x512
  bf16* kb  = qb + 2097152;
  bf16* vb  = kb + 2097152;       // 4096x1024
  bf16* vT  = vb + 4194304;       // 1024x4096
  bf16* x   = vT + 4194304;       // 4096x1024

  convert_bf16<<<128, 256, 0, stream>>>(Q, Qb, 2097152);
  convert_bf16<<<128, 256, 0, stream>>>(Km, Kb, 2097152);
  convert_bf16<<<128, 256, 0, stream>>>(V, Vb, 2097152);
  convert_bf16<<<32, 256, 0, stream>>>(Wo, Wob, 524288);
  pack_w<<<512, 256, 0, stream>>>(Wq, Wqt, 128, 262144);
  pack_w<<<512, 256, 0, stream>>>(Wk, Wkt, 128, 262144);
  pack_w<<<512, 256, 0, stream>>>(Wv, Wvt, 256, 524288);

  gemm_bt<bf16><<<dim3(64, 8), 256, 0, stream>>>(Qb, Wqt, qb, 4096, 512, 512);
  gemm_bt<bf16><<<dim3(64, 8), 256, 0, stream>>>(Kb, Wkt, kb, 4096, 512, 512);
  gemm_bt<bf16><<<dim3(64, 16), 256, 0, stream>>>(Vb, Wvt, vb, 4096, 1024, 512);
  transpose_bf16<<<dim3(64, 16), 256, 0, stream>>>(vb, vT, 4096, 1024);

  attn<<<256, 512, 0, stream>>>(qb, kb, vT, x);

  gemm_bt<float><<<dim3(64, 8), 256, 0, stream>>>(x, Wob, out, 4096, 512, 1024);
}

// Round 3
// 249.376 us; speedup vs baseline: 3.3048x; 1.4458x over previous
//
#include <hip/hip_runtime.h>
#include <hip/hip_bf16.h>
#include <type_traits>

typedef __hip_bfloat16 bf16;
typedef __attribute__((ext_vector_type(8))) short bf16x8;
typedef __attribute__((ext_vector_type(4))) float f32x4;

#define N_LOC 4096
#define DMODEL 512
#define NHEAD 4
#define DK 128
#define DV 256

__device__ __forceinline__ bf16 to_bf16(float f) { return __float2bfloat16(f); }

// async global->LDS DMA, 16B per lane; LDS dest = wave-uniform base + lane*16
__device__ __forceinline__ void dma16(const bf16* g, bf16* l) {
  __builtin_amdgcn_global_load_lds((const __attribute__((address_space(1))) unsigned int*)g,
                                   (__attribute__((address_space(3))) unsigned int*)l, 16, 0, 0);
}

// ---------------- fused conversion f32 -> bf16 for Q,K,V,Wo ----------------
__global__ __launch_bounds__(256) void convert_all(const float* __restrict__ Q,
                                                   const float* __restrict__ K,
                                                   const float* __restrict__ V,
                                                   const float* __restrict__ Wo,
                                                   bf16* __restrict__ Qb, bf16* __restrict__ Kb,
                                                   bf16* __restrict__ Vb, bf16* __restrict__ Wob) {
  long i = ((long)blockIdx.x * 256 + threadIdx.x) * 8;
  const float* src;
  bf16* dst;
  long off;
  if (i < 2097152)      { src = Q;  dst = Qb;  off = i; }
  else if (i < 4194304) { src = K;  dst = Kb;  off = i - 2097152; }
  else if (i < 6291456) { src = V;  dst = Vb;  off = i - 4194304; }
  else                  { src = Wo; dst = Wob; off = i - 6291456; }
  float4 a = *(const float4*)&src[off];
  float4 b = *(const float4*)&src[off + 4];
  union { bf16 h[8]; bf16x8 v; } u;
  u.h[0] = to_bf16(a.x); u.h[1] = to_bf16(a.y); u.h[2] = to_bf16(a.z); u.h[3] = to_bf16(a.w);
  u.h[4] = to_bf16(b.x); u.h[5] = to_bf16(b.y); u.h[6] = to_bf16(b.z); u.h[7] = to_bf16(b.w);
  *(bf16x8*)&dst[off] = u.v;
}

// ---------------- W pack: [H][512][DH] -> Bt [H*DH][512], LDS-tiled transpose ----------------
__global__ __launch_bounds__(256) void pack_wt(const float* __restrict__ Wq,
                                               const float* __restrict__ Wk,
                                               const float* __restrict__ Wv,
                                               bf16* __restrict__ oq, bf16* __restrict__ ok,
                                               bf16* __restrict__ ov) {
  int z = blockIdx.z;
  const float* W = (z == 0) ? Wq : (z == 1) ? Wk : Wv;
  bf16* out = (z == 0) ? oq : (z == 1) ? ok : ov;
  int DH = (z == 2) ? 256 : 128;
  int nt = DH >> 6;
  int y = blockIdx.y;
  if (y >= 4 * nt) return;
  int h = y / nt, tt = y - h * nt;
  int d0 = blockIdx.x * 64, t0 = tt * 64;
  __shared__ float tile[64][65];
  for (int i = threadIdx.x; i < 4096; i += 256) {
    int r = i >> 6, c = i & 63;
    tile[r][c] = W[((size_t)h * 512 + d0 + r) * DH + t0 + c];
  }
  __syncthreads();
  for (int i = threadIdx.x; i < 4096; i += 256) {
    int t = i >> 6, d = i & 63;
    out[((size_t)(h * DH + t0 + t)) * 512 + d0 + d] = to_bf16(tile[d][t]);
  }
}

// ---------------- generic GEMM: C[M][N] = A[M][K] * Bt[N][K]^T ----------------
template <typename OutT>
__global__ __launch_bounds__(256) void gemm_bt(const bf16* __restrict__ A,
                                               const bf16* __restrict__ Bt,
                                               OutT* __restrict__ C, int M, int N, int K) {
  const int LD = 72;
  __shared__ bf16 As[64 * LD];
  __shared__ bf16 Bs[64 * LD];
  int tid = threadIdx.x;
  int lane = tid & 63, w = tid >> 6;
  int quad = lane >> 4, l16 = lane & 15;
  int wm = (w >> 1) * 32, wn = (w & 1) * 32;
  int m0 = blockIdx.x * 64, n0 = blockIdx.y * 64;

  f32x4 acc[2][2] = {};
  for (int k0 = 0; k0 < K; k0 += 64) {
    for (int i = tid; i < 64 * 8; i += 256) {
      int r = i >> 3, c = (i & 7) * 8;
      *(bf16x8*)&As[r * LD + c] = *(const bf16x8*)&A[(long)(m0 + r) * K + k0 + c];
      *(bf16x8*)&Bs[r * LD + c] = *(const bf16x8*)&Bt[(long)(n0 + r) * K + k0 + c];
    }
    __syncthreads();
#pragma unroll
    for (int kk = 0; kk < 2; kk++) {
      bf16x8 af[2], bfr[2];
#pragma unroll
      for (int i = 0; i < 2; i++)
        af[i] = *(const bf16x8*)&As[(wm + i * 16 + l16) * LD + kk * 32 + quad * 8];
#pragma unroll
      for (int j = 0; j < 2; j++)
        bfr[j] = *(const bf16x8*)&Bs[(wn + j * 16 + l16) * LD + kk * 32 + quad * 8];
#pragma unroll
      for (int i = 0; i < 2; i++)
#pragma unroll
        for (int j = 0; j < 2; j++)
          acc[i][j] = __builtin_amdgcn_mfma_f32_16x16x32_bf16(af[i], bfr[j], acc[i][j], 0, 0, 0);
    }
    __syncthreads();
  }
#pragma unroll
  for (int i = 0; i < 2; i++)
#pragma unroll
    for (int j = 0; j < 2; j++)
#pragma unroll
      for (int r = 0; r < 4; r++) {
        long row = m0 + wm + i * 16 + quad * 4 + r;
        long col = n0 + wn + j * 16 + l16;
        if constexpr (std::is_same<OutT, bf16>::value)
          C[row * N + col] = to_bf16(acc[i][j][r]);
        else
          C[row * N + col] = acc[i][j][r];
      }
}

// ---------------- transpose (R x C) -> (C x R), bf16 ----------------
__global__ __launch_bounds__(256) void transpose_bf16(const bf16* __restrict__ in,
                                                      bf16* __restrict__ out, int R, int Cc) {
  __shared__ bf16 t[64][65];
  int r0 = blockIdx.x * 64, c0 = blockIdx.y * 64;
  for (int i = threadIdx.x; i < 64 * 64; i += 256) {
    int r = i >> 6, c = i & 63;
    t[r][c] = in[(long)(r0 + r) * Cc + c0 + c];
  }
  __syncthreads();
  for (int i = threadIdx.x; i < 64 * 64; i += 256) {
    int c = i >> 6, r = i & 63;
    out[(long)(c0 + c) * R + r0 + r] = t[r][c];
  }
}

// ---------------- fused attention ----------------
// qb,kb: [N][512]; vT: [1024][N]; x: [N][1024]
// 512 threads = 8 waves; 64 queries/block; 64-key tiles.
// Work split (wave w: cd=w&3, g=w>>2):
//   S phase : wave computes S[q rows g*32..g*32+31][key col cd*16..] -> kt frags read 2x not 4x
//   PV phase: wave owns q rows g*32.. x dv cols cd*64..cd*64+63 -> vt frags read 2x not 4x
// kt/vt: XOR-swizzled unpadded layouts filled by global_load_lds DMA (granule G of
// row r stored at position G^(r&7)) -> conflict-free frag reads, no staging VGPRs.
// L (softmax denom) via all-ones register B-fragment on cd==3 waves.
__global__ __launch_bounds__(512, 4) void attn(const bf16* __restrict__ qb,
                                               const bf16* __restrict__ kb,
                                               const bf16* __restrict__ vT,
                                               bf16* __restrict__ x) {
  __shared__ __align__(16) bf16 kt[64 * 128];   // [key][dk] swizzled, 16 KB
  __shared__ __align__(16) bf16 vt[256 * 64];   // [dv][key] swizzled, 32 KB
  __shared__ __align__(16) bf16 pt[64 * 72];    // [q][key], padded (+8) -> 2-way max
  __shared__ float Lrow[64];

  const int head = blockIdx.x & 3;
  const int q0 = (blockIdx.x >> 2) * 64;
  const int tid = threadIdx.x;
  const int lane = tid & 63, w = tid >> 6;
  const int quad = lane >> 4, l16 = lane & 15;
  const int cd = w & 3;   // S: key-col tile; PV: dv group
  const int g = w >> 2;   // q half

  // all-ones B-fragment: B[n][k] = (n==0) -> D[q][0] = sum_k P[q][k]
  bf16x8 onesf;
  {
    union { bf16 h[8]; bf16x8 v; } u;
    bf16 one = to_bf16(1.0f), zero = to_bf16(0.0f);
#pragma unroll
    for (int j = 0; j < 8; j++) u.h[j] = (l16 == 0) ? one : zero;
    onesf = u.v;
  }

  // preload q fragments (A-layout: m=l16, k=quad*8+j)
  bf16x8 qf[2][4];
#pragma unroll
  for (int i = 0; i < 2; i++) {
    const bf16* qrow = &qb[(size_t)(q0 + g * 32 + i * 16 + l16) * 512 + head * 128];
#pragma unroll
    for (int kk = 0; kk < 4; kk++) qf[i][kk] = *(const bf16x8*)&qrow[kk * 32 + quad * 8];
  }

  f32x4 oacc[2][4] = {};
  f32x4 oL[2] = {};
  const float scale = 1.0f / 64.0f;  // 1/sqrt(4096)

  for (int key0 = 0; key0 < N_LOC; key0 += 64) {
    // ---- DMA staging: kt chunks 2w..2w+1, vt chunks 4w..4w+3 (1 KB each) ----
#pragma unroll
    for (int t2 = 0; t2 < 2; t2++) {
      int j = 2 * w + t2;
      int r = 4 * j + (lane >> 4);            // key row 0..63
      int p = lane & 15;                      // stored granule position
      int G = (p & 8) | ((p ^ r) & 7);        // source granule (inverse swizzle)
      dma16(&kb[(size_t)(key0 + r) * 512 + head * 128 + G * 8], &kt[j * 512]);
    }
#pragma unroll
    for (int t2 = 0; t2 < 4; t2++) {
      int j = 4 * w + t2;
      int r = 8 * j + (lane >> 3);            // dv row 0..255
      int p = lane & 7;
      int G = (p ^ r) & 7;
      dma16(&vT[(size_t)(head * 256 + r) * 4096 + key0 + G * 8], &vt[j * 512]);
    }
    __syncthreads();  // drains DMA (vmcnt) + joins waves

    // ---- S = q @ k^T : this wave: q rows g*32..+31, key col cd ----
    f32x4 sacc[2] = {};
#pragma unroll
    for (int kk = 0; kk < 4; kk++) {
      int R = cd * 16 + l16;
      int G = kk * 4 + quad;
      bf16x8 kf = *(const bf16x8*)&kt[R * 128 + (((G ^ R) & 7) | (G & 8)) * 8];
      sacc[0] = __builtin_amdgcn_mfma_f32_16x16x32_bf16(qf[0][kk], kf, sacc[0], 0, 0, 0);
      sacc[1] = __builtin_amdgcn_mfma_f32_16x16x32_bf16(qf[1][kk], kf, sacc[1], 0, 0, 0);
    }
#pragma unroll
    for (int i = 0; i < 2; i++)
#pragma unroll
      for (int r = 0; r < 4; r++)
        pt[(g * 32 + i * 16 + quad * 4 + r) * 72 + cd * 16 + l16] =
            to_bf16(__expf(sacc[i][r] * scale));
    __syncthreads();

    // ---- O += P @ v : this wave: q rows g*32..+31, dv cols cd*64..+63 ----
#pragma unroll
    for (int kk = 0; kk < 2; kk++) {
      bf16x8 pf[2];
#pragma unroll
      for (int i = 0; i < 2; i++)
        pf[i] = *(const bf16x8*)&pt[(g * 32 + i * 16 + l16) * 72 + kk * 32 + quad * 8];
#pragma unroll
      for (int c = 0; c < 4; c++) {
        int R = cd * 64 + c * 16 + l16;
        int G = kk * 4 + quad;
        bf16x8 vf = *(const bf16x8*)&vt[R * 64 + ((G ^ R) & 7) * 8];
#pragma unroll
        for (int i = 0; i < 2; i++)
          oacc[i][c] = __builtin_amdgcn_mfma_f32_16x16x32_bf16(pf[i], vf, oacc[i][c], 0, 0, 0);
      }
      if (cd == 3) {  // wave-uniform: L column
#pragma unroll
        for (int i = 0; i < 2; i++)
          oL[i] = __builtin_amdgcn_mfma_f32_16x16x32_bf16(pf[i], onesf, oL[i], 0, 0, 0);
      }
    }
    __syncthreads();
  }

  // L at lanes l16==0 of cd==3 waves (C-layout col 0)
  if (cd == 3 && l16 == 0) {
#pragma unroll
    for (int i = 0; i < 2; i++)
#pragma unroll
      for (int r = 0; r < 4; r++) Lrow[g * 32 + i * 16 + quad * 4 + r] = oL[i][r];
  }
  __syncthreads();

  // normalize + write x[n][head*256 + dv]
#pragma unroll
  for (int i = 0; i < 2; i++)
#pragma unroll
    for (int c = 0; c < 4; c++)
#pragma unroll
      for (int r = 0; r < 4; r++) {
        int row = g * 32 + i * 16 + quad * 4 + r;
        float v = oacc[i][c][r] / Lrow[row];
        x[(size_t)(q0 + row) * 1024 + head * 256 + cd * 64 + c * 16 + l16] = to_bf16(v);
      }
}

// ---------------- launch ----------------
extern "C" void kernel_launch(void* const* d_in, const int* in_sizes, int n_in,
                              void* d_out, int out_size, void* d_ws, size_t ws_size,
                              hipStream_t stream) {
  const float* Q  = (const float*)d_in[0];
  const float* Km = (const float*)d_in[1];
  const float* V  = (const float*)d_in[2];
  const float* Wq = (const float*)d_in[3];
  const float* Wk = (const float*)d_in[4];
  const float* Wv = (const float*)d_in[5];
  const float* Wo = (const float*)d_in[6];
  float* out = (float*)d_out;

  bf16* ws  = (bf16*)d_ws;
  bf16* Qb  = ws;                 // 4096x512
  bf16* Kb  = Qb + 2097152;
  bf16* Vb  = Kb + 2097152;
  bf16* Wqt = Vb + 2097152;       // 512x512  (Bt)
  bf16* Wkt = Wqt + 262144;
  bf16* Wvt = Wkt + 262144;       // 1024x512 (Bt)
  bf16* Wob = Wvt + 524288;       // 512x1024 (Bt = Wo as-is)
  bf16* qb  = Wob + 524288;       // 4096x512
  bf16* kb  = qb + 2097152;
  bf16* vb  = kb + 2097152;       // 4096x1024
  bf16* vT  = vb + 4194304;       // 1024x4096
  bf16* x   = vT + 4194304;       // 4096x1024

  convert_all<<<3328, 256, 0, stream>>>(Q, Km, V, Wo, Qb, Kb, Vb, Wob);
  pack_wt<<<dim3(8, 16, 3), 256, 0, stream>>>(Wq, Wk, Wv, Wqt, Wkt, Wvt);

  gemm_bt<bf16><<<dim3(64, 8), 256, 0, stream>>>(Qb, Wqt, qb, 4096, 512, 512);
  gemm_bt<bf16><<<dim3(64, 8), 256, 0, stream>>>(Kb, Wkt, kb, 4096, 512, 512);
  gemm_bt<bf16><<<dim3(64, 16), 256, 0, stream>>>(Vb, Wvt, vb, 4096, 1024, 512);
  transpose_bf16<<<dim3(64, 16), 256, 0, stream>>>(vb, vT, 4096, 1024);

  attn<<<256, 512, 0, stream>>>(qb, kb, vT, x);

  gemm_bt<float><<<dim3(64, 8), 256, 0, stream>>>(x, Wob, out, 4096, 512, 1024);
}